// Round 4
// baseline (298.979 us; speedup 1.0000x reference)
//
#include <hip/hip_runtime.h>
#include <math.h>

#define L_ 2048
#define CDIM 384
#define DI 768
#define DSTATE 16
#define RNK 24
#define NCH 64
#define CH 32

struct DirParams { const float *cw, *cb, *xpw, *dtw, *dtb, *Alog, *D; };
struct AllParams { DirParams p[3]; };

__device__ __forceinline__ int pmap(int dir, int l) {
  if (dir == 0) return l;
  if (dir == 1) return 2047 - l;
  return ((l & 7) << 8) + (l >> 3);   // slice perm: (l%8)*256 + l/8
}

// ---------------- LayerNorm: x (C,L) -> xn (L,C) ----------------
__global__ __launch_bounds__(256) void k_ln(const float* __restrict__ x,
    const float* __restrict__ g, const float* __restrict__ b,
    float* __restrict__ xn) {
  int l = blockIdx.x, tid = threadIdx.x;
  __shared__ float vals[CDIM];
  __shared__ float red[4];
  __shared__ float mu_s, rstd_s;
  float s = 0.f;
  for (int c = tid; c < CDIM; c += 256) {
    float v = x[(size_t)c * L_ + l];
    vals[c] = v; s += v;
  }
  for (int o = 32; o; o >>= 1) s += __shfl_down(s, o);
  int wid = tid >> 6, lane = tid & 63;
  if (lane == 0) red[wid] = s;
  __syncthreads();
  if (tid == 0) mu_s = (red[0] + red[1] + red[2] + red[3]) / (float)CDIM;
  __syncthreads();
  float mu = mu_s;
  float s2 = 0.f;
  for (int c = tid; c < CDIM; c += 256) { float v = vals[c] - mu; s2 += v * v; }
  for (int o = 32; o; o >>= 1) s2 += __shfl_down(s2, o);
  if (lane == 0) red[wid] = s2;
  __syncthreads();
  if (tid == 0) rstd_s = rsqrtf((red[0] + red[1] + red[2] + red[3]) / (float)CDIM + 1e-5f);
  __syncthreads();
  float rstd = rstd_s;
  for (int c = tid; c < CDIM; c += 256)
    xn[(size_t)l * CDIM + c] = (vals[c] - mu) * rstd * g[c] + b[c];
}

// ---------------- Tiled fp32 GEMM: C[m][n] = sum_k A[m][k]*W[n][k] ----------------
template <bool TRANS_OUT>
__global__ __launch_bounds__(256) void k_gemm(const float* __restrict__ A,
    const float* __restrict__ W, float* __restrict__ Cout,
    const float* __restrict__ resid, int M, int N, int K) {
  __shared__ float As[16][65];
  __shared__ float Bs[16][65];
  int m0 = blockIdx.y * 64, n0 = blockIdx.x * 64;
  int tid = threadIdx.x;
  int lr = tid >> 2;           // 0..63
  int lk = (tid & 3) << 2;     // 0,4,8,12
  int tm = (tid >> 4) << 2;    // 0..60
  int tn = (tid & 15) << 2;    // 0..60
  float acc[4][4] = {};
  for (int k0 = 0; k0 < K; k0 += 16) {
    float4 a = *(const float4*)(A + (size_t)(m0 + lr) * K + k0 + lk);
    float4 w = *(const float4*)(W + (size_t)(n0 + lr) * K + k0 + lk);
    As[lk + 0][lr] = a.x; As[lk + 1][lr] = a.y; As[lk + 2][lr] = a.z; As[lk + 3][lr] = a.w;
    Bs[lk + 0][lr] = w.x; Bs[lk + 1][lr] = w.y; Bs[lk + 2][lr] = w.z; Bs[lk + 3][lr] = w.w;
    __syncthreads();
#pragma unroll
    for (int kk = 0; kk < 16; ++kk) {
      float av[4], bv[4];
#pragma unroll
      for (int i = 0; i < 4; ++i) av[i] = As[kk][tm + i];
#pragma unroll
      for (int j = 0; j < 4; ++j) bv[j] = Bs[kk][tn + j];
#pragma unroll
      for (int i = 0; i < 4; ++i)
#pragma unroll
        for (int j = 0; j < 4; ++j) acc[i][j] = fmaf(av[i], bv[j], acc[i][j]);
    }
    __syncthreads();
  }
  if (!TRANS_OUT) {
#pragma unroll
    for (int i = 0; i < 4; ++i)
#pragma unroll
      for (int j = 0; j < 4; ++j)
        Cout[(size_t)(m0 + tm + i) * N + n0 + tn + j] = acc[i][j];
  } else {
#pragma unroll
    for (int i = 0; i < 4; ++i)
#pragma unroll
      for (int j = 0; j < 4; ++j) {
        size_t idx = (size_t)(n0 + tn + j) * M + (m0 + tm + i);
        Cout[idx] = acc[i][j] + resid[idx];
      }
  }
}

// ---------------- Conv(4, causal, depthwise) + SiLU, per direction ----------------
__global__ __launch_bounds__(256) void k_conv(const float* __restrict__ xz,
    float* __restrict__ xc_all, AllParams P) {
  int dir = blockIdx.y;
  int bx = blockIdx.x;
  int l = bx / 3, dch = bx % 3;
  int d = dch * 256 + threadIdx.x;
  const DirParams& dp = P.p[dir];
  float4 w = *(const float4*)(dp.cw + d * 4);
  float wv[4] = {w.x, w.y, w.z, w.w};
  float acc = dp.cb[d];
#pragma unroll
  for (int k = 0; k < 4; ++k) {
    int ls = l - 3 + k;
    if (ls >= 0) acc = fmaf(wv[k], xz[(size_t)pmap(dir, ls) * 1536 + d], acc);
  }
  float sv = acc / (1.f + __expf(-acc));
  xc_all[(size_t)dir * (L_ * DI) + (size_t)l * DI + d] = sv;
}

// ---------------- x-proj GEMM: dbl[dir][l][0..55] = xc[l][:] @ xpw^T ----------------
// 64x64 tile (N padded 56->64), dbl stored with stride 64.
__global__ __launch_bounds__(256) void k_xgemm(const float* __restrict__ xc_all,
    float* __restrict__ dbl, AllParams P) {
  __shared__ float As[16][65];
  __shared__ float Ws[16][65];
  int dir = blockIdx.z;
  int m0 = blockIdx.y * 64;
  const float* A = xc_all + (size_t)dir * (L_ * DI);
  const float* W = P.p[dir].xpw;           // 56 x 768
  int tid = threadIdx.x;
  int lr = tid >> 2, lk = (tid & 3) << 2;
  int tm = (tid >> 4) << 2, tn = (tid & 15) << 2;
  float acc[4][4] = {};
  for (int k0 = 0; k0 < DI; k0 += 16) {
    float4 a = *(const float4*)(A + (size_t)(m0 + lr) * DI + k0 + lk);
    float4 w = make_float4(0.f, 0.f, 0.f, 0.f);
    if (lr < 56) w = *(const float4*)(W + (size_t)lr * DI + k0 + lk);
    As[lk + 0][lr] = a.x; As[lk + 1][lr] = a.y; As[lk + 2][lr] = a.z; As[lk + 3][lr] = a.w;
    Ws[lk + 0][lr] = w.x; Ws[lk + 1][lr] = w.y; Ws[lk + 2][lr] = w.z; Ws[lk + 3][lr] = w.w;
    __syncthreads();
#pragma unroll
    for (int kk = 0; kk < 16; ++kk) {
      float av[4], bv[4];
#pragma unroll
      for (int i = 0; i < 4; ++i) av[i] = As[kk][tm + i];
#pragma unroll
      for (int j = 0; j < 4; ++j) bv[j] = Ws[kk][tn + j];
#pragma unroll
      for (int i = 0; i < 4; ++i)
#pragma unroll
        for (int j = 0; j < 4; ++j) acc[i][j] = fmaf(av[i], bv[j], acc[i][j]);
    }
    __syncthreads();
  }
#pragma unroll
  for (int i = 0; i < 4; ++i)
#pragma unroll
    for (int j = 0; j < 4; ++j)
      dbl[((size_t)dir * L_ + m0 + tm + i) * 64 + tn + j] = acc[i][j];
}

// ---------------- dt-proj (24->768) + softplus + B/C extract ----------------
__global__ __launch_bounds__(256) void k_dtproj(const float* __restrict__ dbl,
    float* __restrict__ dt_all, float* __restrict__ B_all, float* __restrict__ C_all,
    AllParams P) {
  int dir = blockIdx.y;
  int l0 = blockIdx.x * 16;
  const DirParams& dp = P.p[dir];
  __shared__ float db[16 * 64];
  int tid = threadIdx.x;
  ((float4*)db)[tid] = ((const float4*)(dbl + ((size_t)dir * L_ + l0) * 64))[tid];
  __syncthreads();
  int tok = tid >> 4, dml = tid & 15;
  const float* dbr = db + tok * 64;
  // pull this token's 24-vector into registers once
  float dv[RNK];
#pragma unroll
  for (int r = 0; r < RNK; r += 4) {
    float4 q = *(const float4*)(dbr + r);
    dv[r] = q.x; dv[r + 1] = q.y; dv[r + 2] = q.z; dv[r + 3] = q.w;
  }
  B_all[(dir * L_ + l0 + tok) * DSTATE + dml] = dbr[RNK + dml];
  C_all[(dir * L_ + l0 + tok) * DSTATE + dml] = dbr[RNK + DSTATE + dml];
  for (int k = 0; k < 48; ++k) {
    int d = dml + k * 16;
    float acc = dp.dtb[d];
    const float* wr = dp.dtw + d * RNK;
#pragma unroll
    for (int r = 0; r < RNK; r += 4) {
      float4 w4 = *(const float4*)(wr + r);
      acc = fmaf(w4.x, dv[r], acc);
      acc = fmaf(w4.y, dv[r + 1], acc);
      acc = fmaf(w4.z, dv[r + 2], acc);
      acc = fmaf(w4.w, dv[r + 3], acc);
    }
    float sp = fmaxf(acc, 0.f) + log1pf(__expf(-fabsf(acc)));
    dt_all[(size_t)dir * (L_ * DI) + (size_t)(l0 + tok) * DI + d] = sp;
  }
}

// ---------------- Selective scan, chunk-parallel, d-per-thread ----------------
__global__ __launch_bounds__(256) void k_scanA(const float* __restrict__ dt_all,
    const float* __restrict__ xc_all, const float* __restrict__ B_all,
    float* __restrict__ hend, float* __restrict__ Pbuf, AllParams P) {
  int dir = blockIdx.z, ch = blockIdx.y;
  int d = blockIdx.x * 256 + threadIdx.x;
  int l0 = ch * CH;
  const float* dt = dt_all + (size_t)dir * (L_ * DI);
  const float* xc = xc_all + (size_t)dir * (L_ * DI);
  __shared__ float Bsh[CH * DSTATE];
  for (int t = threadIdx.x; t < CH * DSTATE; t += 256)
    Bsh[t] = B_all[(size_t)(dir * L_ + l0) * DSTATE + t];
  float Av[16];
#pragma unroll
  for (int r = 0; r < 4; ++r) {
    float4 q = *(const float4*)(P.p[dir].Alog + (size_t)d * DSTATE + r * 4);
    Av[r * 4 + 0] = -__expf(q.x); Av[r * 4 + 1] = -__expf(q.y);
    Av[r * 4 + 2] = -__expf(q.z); Av[r * 4 + 3] = -__expf(q.w);
  }
  __syncthreads();
  float h[16];
#pragma unroll
  for (int s = 0; s < 16; ++s) h[s] = 0.f;
  float sdt = 0.f;
  float dtv = dt[(size_t)l0 * DI + d];
  float xv  = xc[(size_t)l0 * DI + d];
  for (int ii = 0; ii < CH; ++ii) {
    float dtn = 0.f, xvn = 0.f;
    if (ii + 1 < CH) {                       // 1-deep prefetch pipeline
      dtn = dt[(size_t)(l0 + ii + 1) * DI + d];
      xvn = xc[(size_t)(l0 + ii + 1) * DI + d];
    }
    float dtx = dtv * xv;
    sdt += dtv;
    const float* Bi = Bsh + ii * DSTATE;
#pragma unroll
    for (int s = 0; s < 16; ++s)
      h[s] = fmaf(__expf(dtv * Av[s]), h[s], dtx * Bi[s]);
    dtv = dtn; xv = xvn;
  }
  size_t o = (((size_t)(dir * NCH + ch)) * DI + d) * DSTATE;
#pragma unroll
  for (int s = 0; s < 16; ++s) {
    hend[o + s] = h[s];
    Pbuf[o + s] = __expf(Av[s] * sdt);
  }
}

__global__ __launch_bounds__(256) void k_scanB(float* __restrict__ hend,
    const float* __restrict__ Pbuf) {
  int gid = blockIdx.x * 256 + threadIdx.x;      // 3*768*16 = 36864 threads
  int dir = gid / (DI * DSTATE);
  int rem = gid - dir * (DI * DSTATE);
  size_t base = (size_t)dir * NCH * (DI * DSTATE) + rem;
  float h = 0.f;
#pragma unroll 8
  for (int ch = 0; ch < NCH; ++ch) {
    size_t o = base + (size_t)ch * (DI * DSTATE);
    float p = Pbuf[o];
    float he = hend[o];
    hend[o] = h;                 // h_start for chunk ch
    h = fmaf(p, h, he);
  }
}

__global__ __launch_bounds__(256) void k_scanC(const float* __restrict__ dt_all,
    const float* __restrict__ xc_all, const float* __restrict__ B_all,
    const float* __restrict__ C_all, const float* __restrict__ hstart,
    float* __restrict__ y_all, AllParams P) {
  int dir = blockIdx.z, ch = blockIdx.y;
  int d = blockIdx.x * 256 + threadIdx.x;
  int l0 = ch * CH;
  const float* dt = dt_all + (size_t)dir * (L_ * DI);
  const float* xc = xc_all + (size_t)dir * (L_ * DI);
  float* yp = y_all + (size_t)dir * (L_ * DI);
  __shared__ float Bsh[CH * DSTATE];
  __shared__ float Csh[CH * DSTATE];
  for (int t = threadIdx.x; t < CH * DSTATE; t += 256) {
    Bsh[t] = B_all[(size_t)(dir * L_ + l0) * DSTATE + t];
    Csh[t] = C_all[(size_t)(dir * L_ + l0) * DSTATE + t];
  }
  float Av[16];
#pragma unroll
  for (int r = 0; r < 4; ++r) {
    float4 q = *(const float4*)(P.p[dir].Alog + (size_t)d * DSTATE + r * 4);
    Av[r * 4 + 0] = -__expf(q.x); Av[r * 4 + 1] = -__expf(q.y);
    Av[r * 4 + 2] = -__expf(q.z); Av[r * 4 + 3] = -__expf(q.w);
  }
  float h[16];
  size_t o = (((size_t)(dir * NCH + ch)) * DI + d) * DSTATE;
#pragma unroll
  for (int r = 0; r < 4; ++r) {
    float4 q = *(const float4*)(hstart + o + r * 4);
    h[r * 4 + 0] = q.x; h[r * 4 + 1] = q.y; h[r * 4 + 2] = q.z; h[r * 4 + 3] = q.w;
  }
  __syncthreads();
  float dtv = dt[(size_t)l0 * DI + d];
  float xv  = xc[(size_t)l0 * DI + d];
  for (int ii = 0; ii < CH; ++ii) {
    float dtn = 0.f, xvn = 0.f;
    if (ii + 1 < CH) {
      dtn = dt[(size_t)(l0 + ii + 1) * DI + d];
      xvn = xc[(size_t)(l0 + ii + 1) * DI + d];
    }
    float dtx = dtv * xv;
    const float* Bi = Bsh + ii * DSTATE;
    const float* Ci = Csh + ii * DSTATE;
    float y = 0.f;
#pragma unroll
    for (int s = 0; s < 16; ++s) {
      h[s] = fmaf(__expf(dtv * Av[s]), h[s], dtx * Bi[s]);
      y = fmaf(h[s], Ci[s], y);
    }
    yp[(size_t)(l0 + ii) * DI + d] = y;
    dtv = dtn; xv = xvn;
  }
}

// ---------------- Gate + combine 3 directions -> ysum (L,768) ----------------
__global__ __launch_bounds__(256) void k_gate(const float* __restrict__ y_all,
    const float* __restrict__ xc_all, const float* __restrict__ xz,
    float* __restrict__ ysum, AllParams P) {
  int l = blockIdx.x;
  int lb = 2047 - l;
  int ls = ((l & 255) << 3) + (l >> 8);   // inv of slice perm
  const size_t DSZ = (size_t)L_ * DI;
  for (int dd = threadIdx.x; dd < DI; dd += 256) {
    float yf = y_all[0 * DSZ + (size_t)l * DI + dd] + xc_all[0 * DSZ + (size_t)l * DI + dd] * P.p[0].D[dd];
    float yb = y_all[1 * DSZ + (size_t)lb * DI + dd] + xc_all[1 * DSZ + (size_t)lb * DI + dd] * P.p[1].D[dd];
    float ys = y_all[2 * DSZ + (size_t)ls * DI + dd] + xc_all[2 * DSZ + (size_t)ls * DI + dd] * P.p[2].D[dd];
    float z = xz[(size_t)l * 1536 + DI + dd];
    ysum[(size_t)l * DI + dd] = (yf + yb + ys) * (z / (1.f + __expf(-z)));
  }
}

extern "C" void kernel_launch(void* const* d_in, const int* in_sizes, int n_in,
                              void* d_out, int out_size, void* d_ws, size_t ws_size,
                              hipStream_t stream) {
  const float* x = (const float*)d_in[0];
  const float* ln_g = (const float*)d_in[1];
  const float* ln_b = (const float*)d_in[2];
  const float* in_proj_w = (const float*)d_in[3];
  const float* out_proj_w = (const float*)d_in[4];
  AllParams P;
  for (int dir = 0; dir < 3; ++dir) {
    int base = 5 + dir * 7;
    P.p[dir].cw  = (const float*)d_in[base + 0];
    P.p[dir].cb  = (const float*)d_in[base + 1];
    P.p[dir].xpw = (const float*)d_in[base + 2];
    P.p[dir].dtw = (const float*)d_in[base + 3];
    P.p[dir].dtb = (const float*)d_in[base + 4];
    P.p[dir].Alog= (const float*)d_in[base + 5];
    P.p[dir].D   = (const float*)d_in[base + 6];
  }
  float* ws = (float*)d_ws;
  const size_t SZ_XN = (size_t)L_ * CDIM;             // 786432
  const size_t SZ_XZ = (size_t)L_ * 1536;             // 3145728
  const size_t SZ_DI = (size_t)L_ * DI;               // 1572864
  const size_t SZ_BS = (size_t)L_ * DSTATE;           // 32768
  const size_t SZ_H  = (size_t)3 * NCH * DI * DSTATE; // 2359296 == SZ_XN + SZ_DI
  // Aliasing plan (lifetime-checked):
  //   dbl (393216 floats) aliases xn head: xn dead after gemm1 (k_xgemm runs later);
  //     dbl dead after k_dtproj, before hend (same region) is written by scanA.
  //   hend aliases [xn][ysum]: ysum written by k_gate only after scanC consumed hend.
  //   Pbuf aliases y_a head: Pbuf dead after scanB; scanC then overwrites y_a.
  float* xn   = ws;                   // dead after gemm1
  float* dbl  = ws;                   // live xgemm -> dtproj
  float* ysum = ws + SZ_XN;           // written by k_gate
  float* hend = ws;                   // SZ_H, overlays xn+ysum exactly
  float* xz   = ws + SZ_H;
  float* xc_a = xz + SZ_XZ;
  float* dt_a = xc_a + 3 * SZ_DI;
  float* B_a  = dt_a + 3 * SZ_DI;
  float* C_a  = B_a + 3 * SZ_BS;
  float* y_a  = C_a + 3 * SZ_BS;
  float* Pbuf = y_a;                  // first SZ_H floats of y_a

  k_ln<<<L_, 256, 0, stream>>>(x, ln_g, ln_b, xn);
  k_gemm<false><<<dim3(1536 / 64, L_ / 64), 256, 0, stream>>>(
      xn, in_proj_w, xz, nullptr, L_, 1536, CDIM);
  k_conv<<<dim3(L_ * 3, 3), 256, 0, stream>>>(xz, xc_a, P);
  k_xgemm<<<dim3(1, L_ / 64, 3), 256, 0, stream>>>(xc_a, dbl, P);
  k_dtproj<<<dim3(L_ / 16, 3), 256, 0, stream>>>(dbl, dt_a, B_a, C_a, P);
  k_scanA<<<dim3(DI / 256, NCH, 3), 256, 0, stream>>>(dt_a, xc_a, B_a, hend, Pbuf, P);
  k_scanB<<<144, 256, 0, stream>>>(hend, Pbuf);
  k_scanC<<<dim3(DI / 256, NCH, 3), 256, 0, stream>>>(dt_a, xc_a, B_a, C_a, hend, y_a, P);
  k_gate<<<L_, 256, 0, stream>>>(y_a, xc_a, xz, ysum, P);
  k_gemm<true><<<dim3(CDIM / 64, L_ / 64), 256, 0, stream>>>(
      ysum, out_proj_w, (float*)d_out, x, L_, CDIM, DI);
}

// Round 5
// 196.140 us; speedup vs baseline: 1.5243x; 1.5243x over previous
//
#include <hip/hip_runtime.h>
#include <math.h>

#define L_ 2048
#define CDIM 384
#define DI 768
#define DSTATE 16
#define RNK 24
#define NCH 64
#define CH 32

typedef __attribute__((ext_vector_type(8))) short short8;
typedef __attribute__((ext_vector_type(4))) float f32x4;
typedef unsigned short ushort_t;

struct DirParams { const float *cw, *cb, *xpw, *dtw, *dtb, *Alog, *D; };
struct AllParams { DirParams p[3]; };

__device__ __forceinline__ int pmap(int dir, int l) {
  if (dir == 0) return l;
  if (dir == 1) return 2047 - l;
  return ((l & 7) << 8) + (l >> 3);   // slice perm: (l%8)*256 + l/8
}

__device__ __forceinline__ ushort_t f2b(float f) {  // fp32 -> bf16 RNE
  unsigned u = __float_as_uint(f);
  return (ushort_t)((u + 0x7FFFu + ((u >> 16) & 1u)) >> 16);
}

// ---------------- weight casts ----------------
__global__ __launch_bounds__(256) void k_cast(const float* __restrict__ src,
    ushort_t* __restrict__ dst, int n4) {
  int i = blockIdx.x * 256 + threadIdx.x;
  if (i < n4) {
    float4 v = ((const float4*)src)[i];
    ushort4 o = { f2b(v.x), f2b(v.y), f2b(v.z), f2b(v.w) };
    ((ushort4*)dst)[i] = o;
  }
}

// wh3[dir][j][k] = j<56 ? xpw[j][k] : 0   (64x768 padded)
__global__ __launch_bounds__(256) void k_padw3(AllParams P, ushort_t* __restrict__ wh3) {
  int dir = blockIdx.y;
  int idx = blockIdx.x * 256 + threadIdx.x;   // 0 .. 64*768-1
  int j = idx / DI, k = idx - j * DI;
  float v = (j < 56) ? P.p[dir].xpw[(size_t)j * DI + k] : 0.f;
  wh3[(size_t)dir * (64 * DI) + idx] = f2b(v);
}

// ---------------- LayerNorm: x (C,L) -> xnh (L,C) bf16 ----------------
__global__ __launch_bounds__(256) void k_ln(const float* __restrict__ x,
    const float* __restrict__ g, const float* __restrict__ b,
    ushort_t* __restrict__ xnh) {
  int l = blockIdx.x, tid = threadIdx.x;
  __shared__ float vals[CDIM];
  __shared__ float red[4];
  __shared__ float mu_s, rstd_s;
  float s = 0.f;
  for (int c = tid; c < CDIM; c += 256) {
    float v = x[(size_t)c * L_ + l];
    vals[c] = v; s += v;
  }
  for (int o = 32; o; o >>= 1) s += __shfl_down(s, o);
  int wid = tid >> 6, lane = tid & 63;
  if (lane == 0) red[wid] = s;
  __syncthreads();
  if (tid == 0) mu_s = (red[0] + red[1] + red[2] + red[3]) / (float)CDIM;
  __syncthreads();
  float mu = mu_s;
  float s2 = 0.f;
  for (int c = tid; c < CDIM; c += 256) { float v = vals[c] - mu; s2 += v * v; }
  for (int o = 32; o; o >>= 1) s2 += __shfl_down(s2, o);
  if (lane == 0) red[wid] = s2;
  __syncthreads();
  if (tid == 0) rstd_s = rsqrtf((red[0] + red[1] + red[2] + red[3]) / (float)CDIM + 1e-5f);
  __syncthreads();
  float rstd = rstd_s;
  for (int c = tid; c < CDIM; c += 256)
    xnh[(size_t)l * CDIM + c] = f2b((vals[c] - mu) * rstd * g[c] + b[c]);
}

// ---------------- bf16 MFMA GEMM: C[m][n] = sum_k A[m][k]*W[n][k] ----------------
// A: M x K bf16 row-major; W: N x K bf16 row-major. No LDS (L2-resident operands).
// Wave -> 32x32 tile via 2x2 mfma_f32_16x16x32_bf16; block = 4 waves = 64x64.
template <bool TRANS_OUT>
__global__ __launch_bounds__(256) void k_mgemm(const ushort_t* __restrict__ A,
    const ushort_t* __restrict__ W, float* __restrict__ Cout,
    const float* __restrict__ resid, int M, int N, int K) {
  int tid = threadIdx.x;
  int wave = tid >> 6, lane = tid & 63;
  int m0 = blockIdx.y * 64 + (wave >> 1) * 32;
  int n0 = blockIdx.x * 64 + (wave & 1) * 32;
  int r = lane & 15, kseg = (lane >> 4) * 8;
  const ushort_t* Ap0 = A + (size_t)(m0 + r) * K + kseg;
  const ushort_t* Ap1 = Ap0 + (size_t)16 * K;
  const ushort_t* Wp0 = W + (size_t)(n0 + r) * K + kseg;
  const ushort_t* Wp1 = Wp0 + (size_t)16 * K;
  f32x4 acc00 = {}, acc01 = {}, acc10 = {}, acc11 = {};
  for (int k0 = 0; k0 < K; k0 += 32) {
    short8 a0 = *(const short8*)(Ap0 + k0);
    short8 a1 = *(const short8*)(Ap1 + k0);
    short8 b0 = *(const short8*)(Wp0 + k0);
    short8 b1 = *(const short8*)(Wp1 + k0);
    acc00 = __builtin_amdgcn_mfma_f32_16x16x32_bf16(a0, b0, acc00, 0, 0, 0);
    acc01 = __builtin_amdgcn_mfma_f32_16x16x32_bf16(a0, b1, acc01, 0, 0, 0);
    acc10 = __builtin_amdgcn_mfma_f32_16x16x32_bf16(a1, b0, acc10, 0, 0, 0);
    acc11 = __builtin_amdgcn_mfma_f32_16x16x32_bf16(a1, b1, acc11, 0, 0, 0);
  }
  int crow = (lane >> 4) * 4, ccol = lane & 15;
  f32x4 accs[2][2] = {{acc00, acc01}, {acc10, acc11}};
#pragma unroll
  for (int i = 0; i < 2; ++i)
#pragma unroll
    for (int j = 0; j < 2; ++j) {
      int gmb = m0 + i * 16 + crow;
      int gn = n0 + j * 16 + ccol;
      if (!TRANS_OUT) {
#pragma unroll
        for (int e = 0; e < 4; ++e)
          Cout[(size_t)(gmb + e) * N + gn] = accs[i][j][e];
      } else {
        size_t idx = (size_t)gn * M + gmb;
        float4 rv = *(const float4*)(resid + idx);
        float4 ov = { accs[i][j][0] + rv.x, accs[i][j][1] + rv.y,
                      accs[i][j][2] + rv.z, accs[i][j][3] + rv.w };
        *(float4*)(Cout + idx) = ov;
      }
    }
}

// ---------------- xproj MFMA GEMM: dbl[dir][l][0..63] = xc[l][:] @ wh3^T ----------------
__global__ __launch_bounds__(256) void k_xgemm(const ushort_t* __restrict__ xch,
    const ushort_t* __restrict__ wh3, float* __restrict__ dbl) {
  int dir = blockIdx.z;
  int tid = threadIdx.x;
  int wave = tid >> 6, lane = tid & 63;
  int m0 = blockIdx.y * 64 + (wave >> 1) * 32;
  int n0 = (wave & 1) * 32;
  int r = lane & 15, kseg = (lane >> 4) * 8;
  const ushort_t* A = xch + (size_t)dir * (L_ * DI);
  const ushort_t* W = wh3 + (size_t)dir * (64 * DI);
  const ushort_t* Ap0 = A + (size_t)(m0 + r) * DI + kseg;
  const ushort_t* Ap1 = Ap0 + (size_t)16 * DI;
  const ushort_t* Wp0 = W + (size_t)(n0 + r) * DI + kseg;
  const ushort_t* Wp1 = Wp0 + (size_t)16 * DI;
  f32x4 acc00 = {}, acc01 = {}, acc10 = {}, acc11 = {};
  for (int k0 = 0; k0 < DI; k0 += 32) {
    short8 a0 = *(const short8*)(Ap0 + k0);
    short8 a1 = *(const short8*)(Ap1 + k0);
    short8 b0 = *(const short8*)(Wp0 + k0);
    short8 b1 = *(const short8*)(Wp1 + k0);
    acc00 = __builtin_amdgcn_mfma_f32_16x16x32_bf16(a0, b0, acc00, 0, 0, 0);
    acc01 = __builtin_amdgcn_mfma_f32_16x16x32_bf16(a0, b1, acc01, 0, 0, 0);
    acc10 = __builtin_amdgcn_mfma_f32_16x16x32_bf16(a1, b0, acc10, 0, 0, 0);
    acc11 = __builtin_amdgcn_mfma_f32_16x16x32_bf16(a1, b1, acc11, 0, 0, 0);
  }
  int crow = (lane >> 4) * 4, ccol = lane & 15;
  f32x4 accs[2][2] = {{acc00, acc01}, {acc10, acc11}};
#pragma unroll
  for (int i = 0; i < 2; ++i)
#pragma unroll
    for (int j = 0; j < 2; ++j) {
      int gmb = m0 + i * 16 + crow;
      int gn = n0 + j * 16 + ccol;
#pragma unroll
      for (int e = 0; e < 4; ++e)
        dbl[((size_t)dir * L_ + gmb + e) * 64 + gn] = accs[i][j][e];
    }
}

// ---------------- Conv(4, causal, depthwise) + SiLU (fp32 + bf16 outputs) ----------------
__global__ __launch_bounds__(256) void k_conv(const float* __restrict__ xz,
    float* __restrict__ xc_all, ushort_t* __restrict__ xch_all, AllParams P) {
  int dir = blockIdx.y;
  int bx = blockIdx.x;
  int l = bx / 3, dch = bx % 3;
  int d = dch * 256 + threadIdx.x;
  const DirParams& dp = P.p[dir];
  float4 w = *(const float4*)(dp.cw + d * 4);
  float wv[4] = {w.x, w.y, w.z, w.w};
  float acc = dp.cb[d];
#pragma unroll
  for (int k = 0; k < 4; ++k) {
    int ls = l - 3 + k;
    if (ls >= 0) acc = fmaf(wv[k], xz[(size_t)pmap(dir, ls) * 1536 + d], acc);
  }
  float sv = acc / (1.f + __expf(-acc));
  size_t o = (size_t)dir * (L_ * DI) + (size_t)l * DI + d;
  xc_all[o] = sv;
  xch_all[o] = f2b(sv);
}

// ---------------- dt-proj (24->768) + softplus + B/C extract ----------------
__global__ __launch_bounds__(256) void k_dtproj(const float* __restrict__ dbl,
    float* __restrict__ dt_all, float* __restrict__ B_all, float* __restrict__ C_all,
    AllParams P) {
  int dir = blockIdx.y;
  int l0 = blockIdx.x * 16;
  const DirParams& dp = P.p[dir];
  __shared__ float db[16 * 64];
  int tid = threadIdx.x;
  ((float4*)db)[tid] = ((const float4*)(dbl + ((size_t)dir * L_ + l0) * 64))[tid];
  __syncthreads();
  int tok = tid >> 4, dml = tid & 15;
  const float* dbr = db + tok * 64;
  float dv[RNK];
#pragma unroll
  for (int r = 0; r < RNK; r += 4) {
    float4 q = *(const float4*)(dbr + r);
    dv[r] = q.x; dv[r + 1] = q.y; dv[r + 2] = q.z; dv[r + 3] = q.w;
  }
  B_all[(dir * L_ + l0 + tok) * DSTATE + dml] = dbr[RNK + dml];
  C_all[(dir * L_ + l0 + tok) * DSTATE + dml] = dbr[RNK + DSTATE + dml];
  for (int k = 0; k < 48; ++k) {
    int d = dml + k * 16;
    float acc = dp.dtb[d];
    const float* wr = dp.dtw + d * RNK;
#pragma unroll
    for (int r = 0; r < RNK; r += 4) {
      float4 w4 = *(const float4*)(wr + r);
      acc = fmaf(w4.x, dv[r], acc);
      acc = fmaf(w4.y, dv[r + 1], acc);
      acc = fmaf(w4.z, dv[r + 2], acc);
      acc = fmaf(w4.w, dv[r + 3], acc);
    }
    float sp = fmaxf(acc, 0.f) + log1pf(__expf(-fabsf(acc)));
    dt_all[(size_t)dir * (L_ * DI) + (size_t)(l0 + tok) * DI + d] = sp;
  }
}

// ---------------- Selective scan, chunk-parallel, d-per-thread ----------------
__global__ __launch_bounds__(256) void k_scanA(const float* __restrict__ dt_all,
    const float* __restrict__ xc_all, const float* __restrict__ B_all,
    float* __restrict__ hend, float* __restrict__ Pbuf, AllParams P) {
  int dir = blockIdx.z, ch = blockIdx.y;
  int d = blockIdx.x * 256 + threadIdx.x;
  int l0 = ch * CH;
  const float* dt = dt_all + (size_t)dir * (L_ * DI);
  const float* xc = xc_all + (size_t)dir * (L_ * DI);
  __shared__ float Bsh[CH * DSTATE];
  for (int t = threadIdx.x; t < CH * DSTATE; t += 256)
    Bsh[t] = B_all[(size_t)(dir * L_ + l0) * DSTATE + t];
  float Av[16];
#pragma unroll
  for (int r = 0; r < 4; ++r) {
    float4 q = *(const float4*)(P.p[dir].Alog + (size_t)d * DSTATE + r * 4);
    Av[r * 4 + 0] = -__expf(q.x); Av[r * 4 + 1] = -__expf(q.y);
    Av[r * 4 + 2] = -__expf(q.z); Av[r * 4 + 3] = -__expf(q.w);
  }
  __syncthreads();
  float h[16];
#pragma unroll
  for (int s = 0; s < 16; ++s) h[s] = 0.f;
  float sdt = 0.f;
  float dtv = dt[(size_t)l0 * DI + d];
  float xv  = xc[(size_t)l0 * DI + d];
  for (int ii = 0; ii < CH; ++ii) {
    float dtn = 0.f, xvn = 0.f;
    if (ii + 1 < CH) {
      dtn = dt[(size_t)(l0 + ii + 1) * DI + d];
      xvn = xc[(size_t)(l0 + ii + 1) * DI + d];
    }
    float dtx = dtv * xv;
    sdt += dtv;
    const float* Bi = Bsh + ii * DSTATE;
#pragma unroll
    for (int s = 0; s < 16; ++s)
      h[s] = fmaf(__expf(dtv * Av[s]), h[s], dtx * Bi[s]);
    dtv = dtn; xv = xvn;
  }
  size_t o = (((size_t)(dir * NCH + ch)) * DI + d) * DSTATE;
#pragma unroll
  for (int s = 0; s < 16; ++s) {
    hend[o + s] = h[s];
    Pbuf[o + s] = __expf(Av[s] * sdt);
  }
}

__global__ __launch_bounds__(256) void k_scanB(float* __restrict__ hend,
    const float* __restrict__ Pbuf) {
  int gid = blockIdx.x * 256 + threadIdx.x;      // 3*768*16 = 36864 threads
  int dir = gid / (DI * DSTATE);
  int rem = gid - dir * (DI * DSTATE);
  size_t base = (size_t)dir * NCH * (DI * DSTATE) + rem;
  float h = 0.f;
#pragma unroll 8
  for (int ch = 0; ch < NCH; ++ch) {
    size_t o = base + (size_t)ch * (DI * DSTATE);
    float p = Pbuf[o];
    float he = hend[o];
    hend[o] = h;                 // h_start for chunk ch
    h = fmaf(p, h, he);
  }
}

__global__ __launch_bounds__(256) void k_scanC(const float* __restrict__ dt_all,
    const float* __restrict__ xc_all, const float* __restrict__ B_all,
    const float* __restrict__ C_all, const float* __restrict__ hstart,
    float* __restrict__ y_all, AllParams P) {
  int dir = blockIdx.z, ch = blockIdx.y;
  int d = blockIdx.x * 256 + threadIdx.x;
  int l0 = ch * CH;
  const float* dt = dt_all + (size_t)dir * (L_ * DI);
  const float* xc = xc_all + (size_t)dir * (L_ * DI);
  float* yp = y_all + (size_t)dir * (L_ * DI);
  __shared__ float Bsh[CH * DSTATE];
  __shared__ float Csh[CH * DSTATE];
  for (int t = threadIdx.x; t < CH * DSTATE; t += 256) {
    Bsh[t] = B_all[(size_t)(dir * L_ + l0) * DSTATE + t];
    Csh[t] = C_all[(size_t)(dir * L_ + l0) * DSTATE + t];
  }
  float Av[16];
#pragma unroll
  for (int r = 0; r < 4; ++r) {
    float4 q = *(const float4*)(P.p[dir].Alog + (size_t)d * DSTATE + r * 4);
    Av[r * 4 + 0] = -__expf(q.x); Av[r * 4 + 1] = -__expf(q.y);
    Av[r * 4 + 2] = -__expf(q.z); Av[r * 4 + 3] = -__expf(q.w);
  }
  float h[16];
  size_t o = (((size_t)(dir * NCH + ch)) * DI + d) * DSTATE;
#pragma unroll
  for (int r = 0; r < 4; ++r) {
    float4 q = *(const float4*)(hstart + o + r * 4);
    h[r * 4 + 0] = q.x; h[r * 4 + 1] = q.y; h[r * 4 + 2] = q.z; h[r * 4 + 3] = q.w;
  }
  __syncthreads();
  float dtv = dt[(size_t)l0 * DI + d];
  float xv  = xc[(size_t)l0 * DI + d];
  for (int ii = 0; ii < CH; ++ii) {
    float dtn = 0.f, xvn = 0.f;
    if (ii + 1 < CH) {
      dtn = dt[(size_t)(l0 + ii + 1) * DI + d];
      xvn = xc[(size_t)(l0 + ii + 1) * DI + d];
    }
    float dtx = dtv * xv;
    const float* Bi = Bsh + ii * DSTATE;
    const float* Ci = Csh + ii * DSTATE;
    float y = 0.f;
#pragma unroll
    for (int s = 0; s < 16; ++s) {
      h[s] = fmaf(__expf(dtv * Av[s]), h[s], dtx * Bi[s]);
      y = fmaf(h[s], Ci[s], y);
    }
    yp[(size_t)(l0 + ii) * DI + d] = y;
    dtv = dtn; xv = xvn;
  }
}

// ---------------- Gate + combine 3 directions -> ysumh (L,768) bf16 ----------------
__global__ __launch_bounds__(256) void k_gate(const float* __restrict__ y_all,
    const float* __restrict__ xc_all, const float* __restrict__ xz,
    ushort_t* __restrict__ ysumh, AllParams P) {
  int l = blockIdx.x;
  int lb = 2047 - l;
  int ls = ((l & 255) << 3) + (l >> 8);   // inv of slice perm
  const size_t DSZ = (size_t)L_ * DI;
  for (int dd = threadIdx.x; dd < DI; dd += 256) {
    float yf = y_all[0 * DSZ + (size_t)l * DI + dd] + xc_all[0 * DSZ + (size_t)l * DI + dd] * P.p[0].D[dd];
    float yb = y_all[1 * DSZ + (size_t)lb * DI + dd] + xc_all[1 * DSZ + (size_t)lb * DI + dd] * P.p[1].D[dd];
    float ys = y_all[2 * DSZ + (size_t)ls * DI + dd] + xc_all[2 * DSZ + (size_t)ls * DI + dd] * P.p[2].D[dd];
    float z = xz[(size_t)l * 1536 + DI + dd];
    ysumh[(size_t)l * DI + dd] = f2b((yf + yb + ys) * (z / (1.f + __expf(-z))));
  }
}

extern "C" void kernel_launch(void* const* d_in, const int* in_sizes, int n_in,
                              void* d_out, int out_size, void* d_ws, size_t ws_size,
                              hipStream_t stream) {
  const float* x = (const float*)d_in[0];
  const float* ln_g = (const float*)d_in[1];
  const float* ln_b = (const float*)d_in[2];
  const float* in_proj_w = (const float*)d_in[3];
  const float* out_proj_w = (const float*)d_in[4];
  AllParams P;
  for (int dir = 0; dir < 3; ++dir) {
    int base = 5 + dir * 7;
    P.p[dir].cw  = (const float*)d_in[base + 0];
    P.p[dir].cb  = (const float*)d_in[base + 1];
    P.p[dir].xpw = (const float*)d_in[base + 2];
    P.p[dir].dtw = (const float*)d_in[base + 3];
    P.p[dir].dtb = (const float*)d_in[base + 4];
    P.p[dir].Alog= (const float*)d_in[base + 5];
    P.p[dir].D   = (const float*)d_in[base + 6];
  }
  float* ws = (float*)d_ws;
  const size_t SZ_XN = (size_t)L_ * CDIM;             // 786432
  const size_t SZ_XZ = (size_t)L_ * 1536;             // 3145728
  const size_t SZ_DI = (size_t)L_ * DI;               // 1572864
  const size_t SZ_BS = (size_t)L_ * DSTATE;           // 32768
  const size_t SZ_H  = (size_t)3 * NCH * DI * DSTATE; // 2359296
  // Aliasing (lifetime-checked):
  //   dbl aliases hend base: dbl live [xgemm..dtproj], hend live [scanA..scanC].
  //   xch (ushort) + Pbuf alias y_a: xch live [conv..xgemm]; Pbuf [scanA..scanB];
  //     y written by scanC after both are dead.
  //   ysumh (ushort) aliases dt_a: dt_a dead after scanC; gate writes ysumh after.
  float* hend = ws;
  float* dbl  = ws;
  float* xz   = ws + SZ_H;
  float* xc_a = xz + SZ_XZ;
  float* dt_a = xc_a + 3 * SZ_DI;
  float* B_a  = dt_a + 3 * SZ_DI;
  float* C_a  = B_a + 3 * SZ_BS;
  float* y_a  = C_a + 3 * SZ_BS;
  ushort_t* xch   = (ushort_t*)y_a;
  float*    Pbuf  = y_a;
  ushort_t* ysumh = (ushort_t*)dt_a;
  float* tail = y_a + 3 * SZ_DI;
  ushort_t* xnh = (ushort_t*)tail;                       // 786432
  ushort_t* wh1 = xnh + SZ_XN;                           // 589824
  ushort_t* wh2 = wh1 + 589824;                          // 294912
  ushort_t* wh3 = wh2 + 294912;                          // 3*64*768 = 147456

  k_cast<<<(589824 / 4 + 255) / 256, 256, 0, stream>>>(in_proj_w, wh1, 589824 / 4);
  k_cast<<<(294912 / 4 + 255) / 256, 256, 0, stream>>>(out_proj_w, wh2, 294912 / 4);
  k_padw3<<<dim3(64 * DI / 256, 3), 256, 0, stream>>>(P, wh3);
  k_ln<<<L_, 256, 0, stream>>>(x, ln_g, ln_b, xnh);
  k_mgemm<false><<<dim3(1536 / 64, L_ / 64), 256, 0, stream>>>(
      xnh, wh1, xz, nullptr, L_, 1536, CDIM);
  k_conv<<<dim3(L_ * 3, 3), 256, 0, stream>>>(xz, xc_a, xch, P);
  k_xgemm<<<dim3(1, L_ / 64, 3), 256, 0, stream>>>(xch, wh3, dbl);
  k_dtproj<<<dim3(L_ / 16, 3), 256, 0, stream>>>(dbl, dt_a, B_a, C_a, P);
  k_scanA<<<dim3(DI / 256, NCH, 3), 256, 0, stream>>>(dt_a, xc_a, B_a, hend, Pbuf, P);
  k_scanB<<<144, 256, 0, stream>>>(hend, Pbuf);
  k_scanC<<<dim3(DI / 256, NCH, 3), 256, 0, stream>>>(dt_a, xc_a, B_a, C_a, hend, y_a, P);
  k_gate<<<L_, 256, 0, stream>>>(y_a, xc_a, xz, ysumh, P);
  k_mgemm<true><<<dim3(CDIM / 64, L_ / 64), 256, 0, stream>>>(
      ysumh, wh2, (float*)d_out, x, L_, CDIM, DI);
}

// Round 6
// 179.002 us; speedup vs baseline: 1.6703x; 1.0957x over previous
//
#include <hip/hip_runtime.h>
#include <math.h>

#define L_ 2048
#define CDIM 384
#define DI 768
#define DSTATE 16
#define RNK 24
#define NCH 64
#define CH 32
#define TOK 32

typedef __attribute__((ext_vector_type(8))) short short8;
typedef __attribute__((ext_vector_type(4))) float f32x4;
typedef unsigned short ushort_t;

struct DirParams { const float *cw, *cb, *xpw, *dtw, *dtb, *Alog, *D; };
struct AllParams { DirParams p[3]; };

__device__ __forceinline__ int pmap(int dir, int l) {
  if (dir == 0) return l;
  if (dir == 1) return 2047 - l;
  return ((l & 7) << 8) + (l >> 3);   // slice perm: (l%8)*256 + l/8
}

__device__ __forceinline__ ushort_t f2b(float f) {  // fp32 -> bf16 RNE
  unsigned u = __float_as_uint(f);
  return (ushort_t)((u + 0x7FFFu + ((u >> 16) & 1u)) >> 16);
}

// ---------------- weight casts ----------------
__global__ __launch_bounds__(256) void k_cast(const float* __restrict__ src,
    ushort_t* __restrict__ dst, int n4) {
  int i = blockIdx.x * 256 + threadIdx.x;
  if (i < n4) {
    float4 v = ((const float4*)src)[i];
    ushort4 o = { f2b(v.x), f2b(v.y), f2b(v.z), f2b(v.w) };
    ((ushort4*)dst)[i] = o;
  }
}

// wh3[dir][j][k] = j<56 ? xpw[j][k] : 0   (64x768 padded)
__global__ __launch_bounds__(256) void k_padw3(AllParams P, ushort_t* __restrict__ wh3) {
  int dir = blockIdx.y;
  int idx = blockIdx.x * 256 + threadIdx.x;   // 0 .. 64*768-1
  int j = idx / DI, k = idx - j * DI;
  float v = (j < 56) ? P.p[dir].xpw[(size_t)j * DI + k] : 0.f;
  wh3[(size_t)dir * (64 * DI) + idx] = f2b(v);
}

// ---------------- LayerNorm: x (C,L) -> xnh (L,C) bf16 ----------------
__global__ __launch_bounds__(256) void k_ln(const float* __restrict__ x,
    const float* __restrict__ g, const float* __restrict__ b,
    ushort_t* __restrict__ xnh) {
  int l = blockIdx.x, tid = threadIdx.x;
  __shared__ float vals[CDIM];
  __shared__ float red[4];
  __shared__ float mu_s, rstd_s;
  float s = 0.f;
  for (int c = tid; c < CDIM; c += 256) {
    float v = x[(size_t)c * L_ + l];
    vals[c] = v; s += v;
  }
  for (int o = 32; o; o >>= 1) s += __shfl_down(s, o);
  int wid = tid >> 6, lane = tid & 63;
  if (lane == 0) red[wid] = s;
  __syncthreads();
  if (tid == 0) mu_s = (red[0] + red[1] + red[2] + red[3]) / (float)CDIM;
  __syncthreads();
  float mu = mu_s;
  float s2 = 0.f;
  for (int c = tid; c < CDIM; c += 256) { float v = vals[c] - mu; s2 += v * v; }
  for (int o = 32; o; o >>= 1) s2 += __shfl_down(s2, o);
  if (lane == 0) red[wid] = s2;
  __syncthreads();
  if (tid == 0) rstd_s = rsqrtf((red[0] + red[1] + red[2] + red[3]) / (float)CDIM + 1e-5f);
  __syncthreads();
  float rstd = rstd_s;
  for (int c = tid; c < CDIM; c += 256)
    xnh[(size_t)l * CDIM + c] = f2b((vals[c] - mu) * rstd * g[c] + b[c]);
}

// ---------------- bf16 MFMA GEMM: C[m][n] = sum_k A[m][k]*W[n][k] ----------------
template <bool TRANS_OUT>
__global__ __launch_bounds__(256) void k_mgemm(const ushort_t* __restrict__ A,
    const ushort_t* __restrict__ W, float* __restrict__ Cout,
    const float* __restrict__ resid, int M, int N, int K) {
  int tid = threadIdx.x;
  int wave = tid >> 6, lane = tid & 63;
  int m0 = blockIdx.y * 64 + (wave >> 1) * 32;
  int n0 = blockIdx.x * 64 + (wave & 1) * 32;
  int r = lane & 15, kseg = (lane >> 4) * 8;
  const ushort_t* Ap0 = A + (size_t)(m0 + r) * K + kseg;
  const ushort_t* Ap1 = Ap0 + (size_t)16 * K;
  const ushort_t* Wp0 = W + (size_t)(n0 + r) * K + kseg;
  const ushort_t* Wp1 = Wp0 + (size_t)16 * K;
  f32x4 acc00 = {}, acc01 = {}, acc10 = {}, acc11 = {};
  for (int k0 = 0; k0 < K; k0 += 32) {
    short8 a0 = *(const short8*)(Ap0 + k0);
    short8 a1 = *(const short8*)(Ap1 + k0);
    short8 b0 = *(const short8*)(Wp0 + k0);
    short8 b1 = *(const short8*)(Wp1 + k0);
    acc00 = __builtin_amdgcn_mfma_f32_16x16x32_bf16(a0, b0, acc00, 0, 0, 0);
    acc01 = __builtin_amdgcn_mfma_f32_16x16x32_bf16(a0, b1, acc01, 0, 0, 0);
    acc10 = __builtin_amdgcn_mfma_f32_16x16x32_bf16(a1, b0, acc10, 0, 0, 0);
    acc11 = __builtin_amdgcn_mfma_f32_16x16x32_bf16(a1, b1, acc11, 0, 0, 0);
  }
  int crow = (lane >> 4) * 4, ccol = lane & 15;
  f32x4 accs[2][2] = {{acc00, acc01}, {acc10, acc11}};
#pragma unroll
  for (int i = 0; i < 2; ++i)
#pragma unroll
    for (int j = 0; j < 2; ++j) {
      int gmb = m0 + i * 16 + crow;
      int gn = n0 + j * 16 + ccol;
      if (!TRANS_OUT) {
#pragma unroll
        for (int e = 0; e < 4; ++e)
          Cout[(size_t)(gmb + e) * N + gn] = accs[i][j][e];
      } else {
        size_t idx = (size_t)gn * M + gmb;
        float4 rv = *(const float4*)(resid + idx);
        float4 ov = { accs[i][j][0] + rv.x, accs[i][j][1] + rv.y,
                      accs[i][j][2] + rv.z, accs[i][j][3] + rv.w };
        *(float4*)(Cout + idx) = ov;
      }
    }
}

// ---------------- xproj MFMA GEMM: dbl[dir][l][0..63] = xc[l][:] @ wh3^T ----------------
__global__ __launch_bounds__(256) void k_xgemm(const ushort_t* __restrict__ xch,
    const ushort_t* __restrict__ wh3, float* __restrict__ dbl) {
  int dir = blockIdx.z;
  int tid = threadIdx.x;
  int wave = tid >> 6, lane = tid & 63;
  int m0 = blockIdx.y * 64 + (wave >> 1) * 32;
  int n0 = (wave & 1) * 32;
  int r = lane & 15, kseg = (lane >> 4) * 8;
  const ushort_t* A = xch + (size_t)dir * (L_ * DI);
  const ushort_t* W = wh3 + (size_t)dir * (64 * DI);
  const ushort_t* Ap0 = A + (size_t)(m0 + r) * DI + kseg;
  const ushort_t* Ap1 = Ap0 + (size_t)16 * DI;
  const ushort_t* Wp0 = W + (size_t)(n0 + r) * DI + kseg;
  const ushort_t* Wp1 = Wp0 + (size_t)16 * DI;
  f32x4 acc00 = {}, acc01 = {}, acc10 = {}, acc11 = {};
  for (int k0 = 0; k0 < DI; k0 += 32) {
    short8 a0 = *(const short8*)(Ap0 + k0);
    short8 a1 = *(const short8*)(Ap1 + k0);
    short8 b0 = *(const short8*)(Wp0 + k0);
    short8 b1 = *(const short8*)(Wp1 + k0);
    acc00 = __builtin_amdgcn_mfma_f32_16x16x32_bf16(a0, b0, acc00, 0, 0, 0);
    acc01 = __builtin_amdgcn_mfma_f32_16x16x32_bf16(a0, b1, acc01, 0, 0, 0);
    acc10 = __builtin_amdgcn_mfma_f32_16x16x32_bf16(a1, b0, acc10, 0, 0, 0);
    acc11 = __builtin_amdgcn_mfma_f32_16x16x32_bf16(a1, b1, acc11, 0, 0, 0);
  }
  int crow = (lane >> 4) * 4, ccol = lane & 15;
  f32x4 accs[2][2] = {{acc00, acc01}, {acc10, acc11}};
#pragma unroll
  for (int i = 0; i < 2; ++i)
#pragma unroll
    for (int j = 0; j < 2; ++j) {
      int gmb = m0 + i * 16 + crow;
      int gn = n0 + j * 16 + ccol;
#pragma unroll
      for (int e = 0; e < 4; ++e)
        dbl[((size_t)dir * L_ + gmb + e) * 64 + gn] = accs[i][j][e];
    }
}

// ---------------- Conv(4, causal, depthwise) + SiLU (fp32 + bf16 outputs) ----------------
__global__ __launch_bounds__(256) void k_conv(const float* __restrict__ xz,
    float* __restrict__ xc_all, ushort_t* __restrict__ xch_all, AllParams P) {
  int dir = blockIdx.y;
  int bx = blockIdx.x;
  int l = bx / 3, dch = bx % 3;
  int d = dch * 256 + threadIdx.x;
  const DirParams& dp = P.p[dir];
  float4 w = *(const float4*)(dp.cw + d * 4);
  float wv[4] = {w.x, w.y, w.z, w.w};
  float acc = dp.cb[d];
#pragma unroll
  for (int k = 0; k < 4; ++k) {
    int ls = l - 3 + k;
    if (ls >= 0) acc = fmaf(wv[k], xz[(size_t)pmap(dir, ls) * 1536 + d], acc);
  }
  float sv = acc / (1.f + __expf(-acc));
  size_t o = (size_t)dir * (L_ * DI) + (size_t)l * DI + d;
  xc_all[o] = sv;
  xch_all[o] = f2b(sv);
}

// ---------------- dt-proj (24->768) + softplus + B/C extract ----------------
// Thread <-> channel d; dtw row in registers (loaded once); 32 tokens staged in LDS.
__global__ __launch_bounds__(256) void k_dtproj(const float* __restrict__ dbl,
    float* __restrict__ dt_all, float* __restrict__ B_all, float* __restrict__ C_all,
    AllParams P) {
  int dir = blockIdx.z;
  int l0 = blockIdx.y * TOK;
  int d = blockIdx.x * 256 + threadIdx.x;
  const DirParams& dp = P.p[dir];
  __shared__ float db[TOK * 24];
  int tid = threadIdx.x;
  // stage dbl[l0..l0+TOK)[0..24) -> LDS (rows of 6 float4s)
  for (int idx = tid; idx < TOK * 6; idx += 256) {
    int row = idx / 6, q = idx - row * 6;
    float4 v = *(const float4*)(dbl + ((size_t)dir * L_ + l0 + row) * 64 + q * 4);
    *(float4*)(db + row * 24 + q * 4) = v;
  }
  // B/C extraction: one x-block per (dir, token-block) handles it
  if (blockIdx.x == 0) {
    for (int idx = tid; idx < TOK * DSTATE; idx += 256) {
      int ii = idx >> 4, s = idx & 15;
      const float* src = dbl + ((size_t)dir * L_ + l0 + ii) * 64;
      B_all[((size_t)dir * L_ + l0 + ii) * DSTATE + s] = src[RNK + s];
      C_all[((size_t)dir * L_ + l0 + ii) * DSTATE + s] = src[RNK + DSTATE + s];
    }
  }
  // per-thread dtw row in registers
  float wr[RNK];
  const float* w = dp.dtw + (size_t)d * RNK;
#pragma unroll
  for (int r = 0; r < RNK; r += 4) {
    float4 q = *(const float4*)(w + r);
    wr[r] = q.x; wr[r + 1] = q.y; wr[r + 2] = q.z; wr[r + 3] = q.w;
  }
  float bias = dp.dtb[d];
  __syncthreads();
  float* dtp = dt_all + (size_t)dir * (L_ * DI);
  for (int ii = 0; ii < TOK; ++ii) {
    float acc = bias;
    const float* dr = db + ii * 24;         // wave-uniform LDS reads (broadcast)
#pragma unroll
    for (int r = 0; r < RNK; ++r) acc = fmaf(wr[r], dr[r], acc);
    float sp = fmaxf(acc, 0.f) + log1pf(__expf(-fabsf(acc)));
    dtp[(size_t)(l0 + ii) * DI + d] = sp;   // coalesced
  }
}

// ---------------- Selective scan, chunk-parallel, d-per-thread ----------------
__global__ __launch_bounds__(256) void k_scanA(const float* __restrict__ dt_all,
    const float* __restrict__ xc_all, const float* __restrict__ B_all,
    float* __restrict__ hend, float* __restrict__ Pbuf, AllParams P) {
  int dir = blockIdx.z, ch = blockIdx.y;
  int d = blockIdx.x * 256 + threadIdx.x;
  int l0 = ch * CH;
  const float* dt = dt_all + (size_t)dir * (L_ * DI);
  const float* xc = xc_all + (size_t)dir * (L_ * DI);
  __shared__ float Bsh[CH * DSTATE];
  for (int t = threadIdx.x; t < CH * DSTATE; t += 256)
    Bsh[t] = B_all[(size_t)(dir * L_ + l0) * DSTATE + t];
  float Av[16];
#pragma unroll
  for (int r = 0; r < 4; ++r) {
    float4 q = *(const float4*)(P.p[dir].Alog + (size_t)d * DSTATE + r * 4);
    Av[r * 4 + 0] = -__expf(q.x); Av[r * 4 + 1] = -__expf(q.y);
    Av[r * 4 + 2] = -__expf(q.z); Av[r * 4 + 3] = -__expf(q.w);
  }
  __syncthreads();
  float h[16];
#pragma unroll
  for (int s = 0; s < 16; ++s) h[s] = 0.f;
  float sdt = 0.f;
  float dtv = dt[(size_t)l0 * DI + d];
  float xv  = xc[(size_t)l0 * DI + d];
  for (int ii = 0; ii < CH; ++ii) {
    float dtn = 0.f, xvn = 0.f;
    if (ii + 1 < CH) {
      dtn = dt[(size_t)(l0 + ii + 1) * DI + d];
      xvn = xc[(size_t)(l0 + ii + 1) * DI + d];
    }
    float dtx = dtv * xv;
    sdt += dtv;
    const float* Bi = Bsh + ii * DSTATE;
#pragma unroll
    for (int s = 0; s < 16; ++s)
      h[s] = fmaf(__expf(dtv * Av[s]), h[s], dtx * Bi[s]);
    dtv = dtn; xv = xvn;
  }
  size_t o = (((size_t)(dir * NCH + ch)) * DI + d) * DSTATE;
#pragma unroll
  for (int s = 0; s < 16; ++s) {
    hend[o + s] = h[s];
    Pbuf[o + s] = __expf(Av[s] * sdt);
  }
}

__global__ __launch_bounds__(256) void k_scanB(float* __restrict__ hend,
    const float* __restrict__ Pbuf) {
  int gid = blockIdx.x * 256 + threadIdx.x;      // 3*768*16 = 36864 threads
  int dir = gid / (DI * DSTATE);
  int rem = gid - dir * (DI * DSTATE);
  size_t base = (size_t)dir * NCH * (DI * DSTATE) + rem;
  float h = 0.f;
#pragma unroll 8
  for (int ch = 0; ch < NCH; ++ch) {
    size_t o = base + (size_t)ch * (DI * DSTATE);
    float p = Pbuf[o];
    float he = hend[o];
    hend[o] = h;                 // h_start for chunk ch
    h = fmaf(p, h, he);
  }
}

__global__ __launch_bounds__(256) void k_scanC(const float* __restrict__ dt_all,
    const float* __restrict__ xc_all, const float* __restrict__ B_all,
    const float* __restrict__ C_all, const float* __restrict__ hstart,
    float* __restrict__ y_all, AllParams P) {
  int dir = blockIdx.z, ch = blockIdx.y;
  int d = blockIdx.x * 256 + threadIdx.x;
  int l0 = ch * CH;
  const float* dt = dt_all + (size_t)dir * (L_ * DI);
  const float* xc = xc_all + (size_t)dir * (L_ * DI);
  float* yp = y_all + (size_t)dir * (L_ * DI);
  __shared__ float Bsh[CH * DSTATE];
  __shared__ float Csh[CH * DSTATE];
  for (int t = threadIdx.x; t < CH * DSTATE; t += 256) {
    Bsh[t] = B_all[(size_t)(dir * L_ + l0) * DSTATE + t];
    Csh[t] = C_all[(size_t)(dir * L_ + l0) * DSTATE + t];
  }
  float Av[16];
#pragma unroll
  for (int r = 0; r < 4; ++r) {
    float4 q = *(const float4*)(P.p[dir].Alog + (size_t)d * DSTATE + r * 4);
    Av[r * 4 + 0] = -__expf(q.x); Av[r * 4 + 1] = -__expf(q.y);
    Av[r * 4 + 2] = -__expf(q.z); Av[r * 4 + 3] = -__expf(q.w);
  }
  float h[16];
  size_t o = (((size_t)(dir * NCH + ch)) * DI + d) * DSTATE;
#pragma unroll
  for (int r = 0; r < 4; ++r) {
    float4 q = *(const float4*)(hstart + o + r * 4);
    h[r * 4 + 0] = q.x; h[r * 4 + 1] = q.y; h[r * 4 + 2] = q.z; h[r * 4 + 3] = q.w;
  }
  __syncthreads();
  float dtv = dt[(size_t)l0 * DI + d];
  float xv  = xc[(size_t)l0 * DI + d];
  for (int ii = 0; ii < CH; ++ii) {
    float dtn = 0.f, xvn = 0.f;
    if (ii + 1 < CH) {
      dtn = dt[(size_t)(l0 + ii + 1) * DI + d];
      xvn = xc[(size_t)(l0 + ii + 1) * DI + d];
    }
    float dtx = dtv * xv;
    const float* Bi = Bsh + ii * DSTATE;
    const float* Ci = Csh + ii * DSTATE;
    float y = 0.f;
#pragma unroll
    for (int s = 0; s < 16; ++s) {
      h[s] = fmaf(__expf(dtv * Av[s]), h[s], dtx * Bi[s]);
      y = fmaf(h[s], Ci[s], y);
    }
    yp[(size_t)(l0 + ii) * DI + d] = y;
    dtv = dtn; xv = xvn;
  }
}

// ---------------- Gate + combine 3 directions -> ysumh (L,768) bf16 ----------------
__global__ __launch_bounds__(256) void k_gate(const float* __restrict__ y_all,
    const float* __restrict__ xc_all, const float* __restrict__ xz,
    ushort_t* __restrict__ ysumh, AllParams P) {
  int l = blockIdx.x;
  int lb = 2047 - l;
  int ls = ((l & 255) << 3) + (l >> 8);   // inv of slice perm
  const size_t DSZ = (size_t)L_ * DI;
  for (int dd = threadIdx.x; dd < DI; dd += 256) {
    float yf = y_all[0 * DSZ + (size_t)l * DI + dd] + xc_all[0 * DSZ + (size_t)l * DI + dd] * P.p[0].D[dd];
    float yb = y_all[1 * DSZ + (size_t)lb * DI + dd] + xc_all[1 * DSZ + (size_t)lb * DI + dd] * P.p[1].D[dd];
    float ys = y_all[2 * DSZ + (size_t)ls * DI + dd] + xc_all[2 * DSZ + (size_t)ls * DI + dd] * P.p[2].D[dd];
    float z = xz[(size_t)l * 1536 + DI + dd];
    ysumh[(size_t)l * DI + dd] = f2b((yf + yb + ys) * (z / (1.f + __expf(-z))));
  }
}

extern "C" void kernel_launch(void* const* d_in, const int* in_sizes, int n_in,
                              void* d_out, int out_size, void* d_ws, size_t ws_size,
                              hipStream_t stream) {
  const float* x = (const float*)d_in[0];
  const float* ln_g = (const float*)d_in[1];
  const float* ln_b = (const float*)d_in[2];
  const float* in_proj_w = (const float*)d_in[3];
  const float* out_proj_w = (const float*)d_in[4];
  AllParams P;
  for (int dir = 0; dir < 3; ++dir) {
    int base = 5 + dir * 7;
    P.p[dir].cw  = (const float*)d_in[base + 0];
    P.p[dir].cb  = (const float*)d_in[base + 1];
    P.p[dir].xpw = (const float*)d_in[base + 2];
    P.p[dir].dtw = (const float*)d_in[base + 3];
    P.p[dir].dtb = (const float*)d_in[base + 4];
    P.p[dir].Alog= (const float*)d_in[base + 5];
    P.p[dir].D   = (const float*)d_in[base + 6];
  }
  float* ws = (float*)d_ws;
  const size_t SZ_XN = (size_t)L_ * CDIM;             // 786432
  const size_t SZ_XZ = (size_t)L_ * 1536;             // 3145728
  const size_t SZ_DI = (size_t)L_ * DI;               // 1572864
  const size_t SZ_BS = (size_t)L_ * DSTATE;           // 32768
  const size_t SZ_H  = (size_t)3 * NCH * DI * DSTATE; // 2359296
  // Aliasing (lifetime-checked):
  //   dbl aliases hend base: dbl live [xgemm..dtproj], hend live [scanA..scanC].
  //   xch (ushort) + Pbuf alias y_a: xch live [conv..xgemm]; Pbuf [scanA..scanB];
  //     y written by scanC after both are dead.
  //   ysumh (ushort) aliases dt_a: dt_a dead after scanC; gate writes ysumh after.
  float* hend = ws;
  float* dbl  = ws;
  float* xz   = ws + SZ_H;
  float* xc_a = xz + SZ_XZ;
  float* dt_a = xc_a + 3 * SZ_DI;
  float* B_a  = dt_a + 3 * SZ_DI;
  float* C_a  = B_a + 3 * SZ_BS;
  float* y_a  = C_a + 3 * SZ_BS;
  ushort_t* xch   = (ushort_t*)y_a;
  float*    Pbuf  = y_a;
  ushort_t* ysumh = (ushort_t*)dt_a;
  float* tail = y_a + 3 * SZ_DI;
  ushort_t* xnh = (ushort_t*)tail;                       // 786432
  ushort_t* wh1 = xnh + SZ_XN;                           // 589824
  ushort_t* wh2 = wh1 + 589824;                          // 294912
  ushort_t* wh3 = wh2 + 294912;                          // 3*64*768 = 147456

  k_cast<<<(589824 / 4 + 255) / 256, 256, 0, stream>>>(in_proj_w, wh1, 589824 / 4);
  k_cast<<<(294912 / 4 + 255) / 256, 256, 0, stream>>>(out_proj_w, wh2, 294912 / 4);
  k_padw3<<<dim3(64 * DI / 256, 3), 256, 0, stream>>>(P, wh3);
  k_ln<<<L_, 256, 0, stream>>>(x, ln_g, ln_b, xnh);
  k_mgemm<false><<<dim3(1536 / 64, L_ / 64), 256, 0, stream>>>(
      xnh, wh1, xz, nullptr, L_, 1536, CDIM);
  k_conv<<<dim3(L_ * 3, 3), 256, 0, stream>>>(xz, xc_a, xch, P);
  k_xgemm<<<dim3(1, L_ / 64, 3), 256, 0, stream>>>(xch, wh3, dbl);
  k_dtproj<<<dim3(DI / 256, L_ / TOK, 3), 256, 0, stream>>>(dbl, dt_a, B_a, C_a, P);
  k_scanA<<<dim3(DI / 256, NCH, 3), 256, 0, stream>>>(dt_a, xc_a, B_a, hend, Pbuf, P);
  k_scanB<<<144, 256, 0, stream>>>(hend, Pbuf);
  k_scanC<<<dim3(DI / 256, NCH, 3), 256, 0, stream>>>(dt_a, xc_a, B_a, C_a, hend, y_a, P);
  k_gate<<<L_, 256, 0, stream>>>(y_a, xc_a, xz, ysumh, P);
  k_mgemm<true><<<dim3(CDIM / 64, L_ / 64), 256, 0, stream>>>(
      ysumh, wh2, (float*)d_out, x, L_, CDIM, DI);
}